// Round 7
// baseline (318.737 us; speedup 1.0000x reference)
//
#include <hip/hip_runtime.h>

// B=128, S=1024, H=256
#define Bb 128
#define Ss 1024
#define Hh 256
#define NEGF 1e9f

typedef short bf16x8 __attribute__((ext_vector_type(8)));
typedef float f32x4 __attribute__((ext_vector_type(4)));

__device__ __forceinline__ short f2bf(float f) {
    union { float f; unsigned u; } c; c.f = f;
    return (short)((c.u + 0x8000u) >> 16);
}

__device__ __forceinline__ float bfhi2f(unsigned u) {
    union { unsigned u; float f; } c; c.u = u & 0xFFFF0000u; return c.f;
}
__device__ __forceinline__ float bflo2f(unsigned u) {
    union { unsigned u; float f; } c; c.u = u << 16; return c.f;
}

__device__ __forceinline__ bf16x8 ld_bf8_f32(const float* p) {
    const float4* p4 = (const float4*)p;
    float4 a = p4[0], b = p4[1];
    bf16x8 r;
    r[0] = f2bf(a.x); r[1] = f2bf(a.y); r[2] = f2bf(a.z); r[3] = f2bf(a.w);
    r[4] = f2bf(b.x); r[5] = f2bf(b.y); r[6] = f2bf(b.z); r[7] = f2bf(b.w);
    return r;
}

__device__ __forceinline__ float fast_tanh(float x) {
    float cl = fminf(fmaxf(x, -10.f), 10.f);
    float e = __expf(2.f * cl);
    return __builtin_fmaf(-2.f, __builtin_amdgcn_rcpf(e + 1.f), 1.f);
}

// async global->LDS, 16B per lane; dest = (wave-uniform) lds base + lane*16
__device__ __forceinline__ void stage16(const short* g, short* l) {
    __builtin_amdgcn_global_load_lds((const __attribute__((address_space(1))) void*)g,
                                     (__attribute__((address_space(3))) void*)l, 16, 0, 0);
}

// ---------------- prep: convert wg,wp -> bf16 (blocks 0..255); qbias_g (256..383)
__global__ __launch_bounds__(256) void prep_kernel(const float* __restrict__ wg,
                                                   const float* __restrict__ wp,
                                                   const float* __restrict__ query,
                                                   const float* __restrict__ wqg,
                                                   const float* __restrict__ bg,
                                                   short* __restrict__ wgb,
                                                   short* __restrict__ wpb,
                                                   float* __restrict__ qbias_g) {
    int blk = blockIdx.x, t = threadIdx.x;
    if (blk < 256) {
        int i = blk * 256 + t;
        wgb[i] = f2bf(wg[i]);
        wpb[i] = f2bf(wp[i]);
    } else {
        int b = blk - 256;
        const float4* qr = (const float4*)(query + b * Hh);
        const float4* wr = (const float4*)(wqg + t * Hh);
        float acc = 0.f;
#pragma unroll 8
        for (int i = 0; i < Hh / 4; ++i) {
            float4 q4 = qr[i], w4 = wr[i];
            acc += q4.x * w4.x + q4.y * w4.y + q4.z * w4.z + q4.w * w4.w;
        }
        qbias_g[b * Hh + t] = acc + bg[t];
    }
}

// ---------------- Main fused GEMM: grid (B, S/64), 4 waves, 16 rows/wave.
// W double-buffered in LDS via global_load_lds (16 n-rows / 8 KB chunks).
// LOADF32: A-frags converted from fp32 ref, bf16 side-output written from regs.
template <int MASKED, int LOADF32>
__global__ __launch_bounds__(256) void scores_mfma(const float* __restrict__ reff,
                                                   const short* __restrict__ refb_in,
                                                   short* __restrict__ refb_out,
                                                   const short* __restrict__ Wbf,
                                                   const float* __restrict__ qbias,
                                                   const float* __restrict__ vvec,
                                                   const int* __restrict__ mask,
                                                   float* __restrict__ out) {
    __shared__ short Wlds[2][4096];   // 2 x 8 KB (16 n-rows per chunk)
    const int b = blockIdx.x;
    const int s0 = blockIdx.y * 64;
    const int t = threadIdx.x;
    const int wave = t >> 6;
    const int lane = t & 63;
    const int nl = lane & 15;
    const int quad = lane >> 4;
    const int rowbase = s0 + wave * 16;   // this wave's 16-row m-tile

    // staging source/dest (verified r3/r4 scheme): thread t feeds read-lane (t&63)
    // of LDS line kb=(t>>6) [soff0] and kb=(t>>6)+4 [soff1]
    const int soff0 = (t & 15) * Hh + (t >> 6) * 32 + ((t >> 4) & 3) * 8;  // shorts
    const int soff1 = soff0 + 128;
    const int dbase0 = wave * 512;          // shorts
    const int dbase1 = 2048 + wave * 512;

    // kick off W chunk 0 staging first (async, overlaps A prologue)
    stage16(Wbf + soff0, &Wlds[0][dbase0]);
    stage16(Wbf + soff1, &Wlds[0][dbase1]);

    // A fragments: A[m=rowbase+nl][k=kb*32+quad*8+j]
    bf16x8 afrag[8];
    {
        const size_t rowoff = ((size_t)b * Ss + rowbase + nl) * Hh;
        if (LOADF32) {
            const float* rp = reff + rowoff;
#pragma unroll
            for (int kb = 0; kb < 8; ++kb)
                afrag[kb] = ld_bf8_f32(rp + kb * 32 + quad * 8);
            short* dst = refb_out + rowoff;
#pragma unroll
            for (int kb = 0; kb < 8; ++kb)
                *(bf16x8*)(dst + kb * 32 + quad * 8) = afrag[kb];
        } else {
            const short* rp = refb_in + rowoff;
#pragma unroll
            for (int kb = 0; kb < 8; ++kb)
                afrag[kb] = *(const bf16x8*)(rp + kb * 32 + quad * 8);
        }
    }
    __syncthreads();

    float sc[4] = {0.f, 0.f, 0.f, 0.f};

    for (int nc = 0; nc < 16; ++nc) {
        const int cur = nc & 1;
        if (nc < 15) {  // async prefetch next 16-row chunk
            const short* g = Wbf + (size_t)(nc + 1) * 16 * Hh;
            stage16(g + soff0, &Wlds[1 - cur][dbase0]);
            stage16(g + soff1, &Wlds[1 - cur][dbase1]);
        }
        const int n = nc * 16 + nl;
        const float qb = qbias[b * Hh + n];
        const float vv = vvec[n];
        bf16x8 bfrag[8];
#pragma unroll
        for (int kb = 0; kb < 8; ++kb)
            bfrag[kb] = *(const bf16x8*)&Wlds[cur][kb * 512 + lane * 8];
        f32x4 c = {0.f, 0.f, 0.f, 0.f};
#pragma unroll
        for (int kb = 0; kb < 8; ++kb)
            c = __builtin_amdgcn_mfma_f32_16x16x32_bf16(afrag[kb], bfrag[kb], c, 0, 0, 0);
        // C/D: col = lane&15 (= n-lane), row = quad*4 + r
#pragma unroll
        for (int r = 0; r < 4; ++r)
            sc[r] += fast_tanh(c[r] + qb) * vv;
        __syncthreads();  // drains prefetch vmcnt + guards buffer swap
    }

    // reduce over the 16 n-lanes within each quad
#pragma unroll
    for (int r = 0; r < 4; ++r) {
        float v = sc[r];
        v += __shfl_xor(v, 1, 64);
        v += __shfl_xor(v, 2, 64);
        v += __shfl_xor(v, 4, 64);
        v += __shfl_xor(v, 8, 64);
        sc[r] = v;
    }

    if (nl == 0) {
#pragma unroll
        for (int r = 0; r < 4; ++r) {
            int m = rowbase + quad * 4 + r;
            float v = sc[r];
            if (MASKED) v -= (float)mask[b * Ss + m] * NEGF;
            out[(size_t)b * Ss + m] = v;
        }
    }
}

// ---------------- Softmax over S per batch (mask applied) -> att ----------------
__global__ __launch_bounds__(1024) void softmax_kernel(const float* __restrict__ scores,
                                                       const int* __restrict__ mask,
                                                       float* __restrict__ att) {
    int b = blockIdx.x, t = threadIdx.x;
    __shared__ float red[16];
    int idx = b * Ss + t;
    float x = scores[idx] - (float)mask[idx] * NEGF;

    float m = x;
#pragma unroll
    for (int o = 1; o < 64; o <<= 1) m = fmaxf(m, __shfl_xor(m, o, 64));
    if ((t & 63) == 0) red[t >> 6] = m;
    __syncthreads();
    float M = red[0];
#pragma unroll
    for (int j = 1; j < 16; ++j) M = fmaxf(M, red[j]);
    __syncthreads();

    float e = __expf(x - M);
    float s = e;
#pragma unroll
    for (int o = 1; o < 64; o <<= 1) s += __shfl_xor(s, o, 64);
    if ((t & 63) == 0) red[t >> 6] = s;
    __syncthreads();
    float S = 0.f;
#pragma unroll
    for (int j = 0; j < 16; ++j) S += red[j];

    att[idx] = e * __builtin_amdgcn_rcpf(S);
}

// ---------------- Glimpse partial (bf16 ref): gpart[b,q,d] = sum_{s in 1/8th q} att*ref
__global__ __launch_bounds__(256) void glimpse_part(const unsigned* __restrict__ refb,
                                                    const float* __restrict__ att,
                                                    float* __restrict__ gpart) {
    int b = blockIdx.x, q = blockIdx.y, t = threadIdx.x;
    const int c = t & 31;      // 16B chunk: d = c*8 .. c*8+7
    const int rg = t >> 5;     // row group 0..7
    __shared__ float part[8][Hh];
    const unsigned* base = refb + ((size_t)(b * Ss + q * 128)) * (Hh / 2);
    const float* ap = att + b * Ss + q * 128;

    float acc[8] = {0.f, 0.f, 0.f, 0.f, 0.f, 0.f, 0.f, 0.f};
#pragma unroll 4
    for (int it = 0; it < 16; ++it) {
        int row = it * 8 + rg;
        float a = ap[row];
        uint4 v = *(const uint4*)(base + (size_t)row * (Hh / 2) + c * 4);
        acc[0] += a * bflo2f(v.x); acc[1] += a * bfhi2f(v.x);
        acc[2] += a * bflo2f(v.y); acc[3] += a * bfhi2f(v.y);
        acc[4] += a * bflo2f(v.z); acc[5] += a * bfhi2f(v.z);
        acc[6] += a * bflo2f(v.w); acc[7] += a * bfhi2f(v.w);
    }
#pragma unroll
    for (int j = 0; j < 8; ++j) part[rg][c * 8 + j] = acc[j];
    __syncthreads();
    float s = 0.f;
#pragma unroll
    for (int g = 0; g < 8; ++g) s += part[g][t];
    gpart[(size_t)(b * 8 + q) * Hh + t] = s;
}

// ---------------- qbias_p[b,h] = sum_d glimpse[b,d]*wqp[h,d] + bp[h] ------------
__global__ __launch_bounds__(256) void qbias_p_kernel(const float* __restrict__ gpart,
                                                      const float* __restrict__ query,
                                                      const float* __restrict__ wqp,
                                                      const float* __restrict__ bp,
                                                      float* __restrict__ out) {
    int b = blockIdx.x, t = threadIdx.x;
    __shared__ __align__(16) float gl[Hh];
    float g = query[b * Hh + t];
#pragma unroll
    for (int q = 0; q < 8; ++q) g += gpart[(b * 8 + q) * Hh + t];
    gl[t] = g;
    __syncthreads();
    const float4* wr = (const float4*)(wqp + t * Hh);
    const float4* gp = (const float4*)gl;
    float acc = 0.f;
#pragma unroll 8
    for (int i = 0; i < Hh / 4; ++i) {
        float4 w4 = wr[i];
        float4 g4 = gp[i];
        acc += w4.x * g4.x + w4.y * g4.y + w4.z * g4.z + w4.w * g4.w;
    }
    out[b * Hh + t] = acc + bp[t];
}

extern "C" void kernel_launch(void* const* d_in, const int* in_sizes, int n_in,
                              void* d_out, int out_size, void* d_ws, size_t ws_size,
                              hipStream_t stream) {
    const float* ref   = (const float*)d_in[0];
    const float* query = (const float*)d_in[1];
    const int*   mask  = (const int*)d_in[2];
    const float* wg    = (const float*)d_in[3];
    const float* bg    = (const float*)d_in[4];
    const float* wqg   = (const float*)d_in[5];
    const float* vg    = (const float*)d_in[6];
    const float* wp    = (const float*)d_in[7];
    const float* bp    = (const float*)d_in[8];
    const float* wqp   = (const float*)d_in[9];
    const float* vp    = (const float*)d_in[10];
    float* out = (float*)d_out;

    char* ws = (char*)d_ws;
    short* ref_bf   = (short*)(ws + 0);          // 64 MB (B*S*H bf16)
    size_t off = (size_t)Bb * Ss * Hh * 2;
    short* wg_bf    = (short*)(ws + off);               off += 131072;
    short* wp_bf    = (short*)(ws + off);               off += 131072;
    float* qbias_g  = (float*)(ws + off);               off += 131072;
    float* qbias_p  = (float*)(ws + off);               off += 131072;
    float* scores_g = (float*)(ws + off);               off += 524288;
    float* att      = (float*)(ws + off);               off += 524288;
    float* gpart    = (float*)(ws + off);               // 1 MB

    prep_kernel<<<384, 256, 0, stream>>>(wg, wp, query, wqg, bg, wg_bf, wp_bf, qbias_g);
    // glimpse scores: fp32 ref in, bf16 ref side-output from A-fragment registers
    scores_mfma<0, 1><<<dim3(Bb, Ss / 64), 256, 0, stream>>>(
        ref, nullptr, ref_bf, wg_bf, qbias_g, vg, nullptr, scores_g);
    softmax_kernel<<<Bb, Ss, 0, stream>>>(scores_g, mask, att);
    glimpse_part<<<dim3(Bb, 8), 256, 0, stream>>>((const unsigned*)ref_bf, att, gpart);
    qbias_p_kernel<<<Bb, Hh, 0, stream>>>(gpart, query, wqp, bp, qbias_p);
    // pointer scores: bf16 ref in, masked, straight to d_out
    scores_mfma<1, 0><<<dim3(Bb, Ss / 64), 256, 0, stream>>>(
        nullptr, ref_bf, nullptr, wp_bf, qbias_p, vp, mask, out);
}

// Round 8
// 314.018 us; speedup vs baseline: 1.0150x; 1.0150x over previous
//
#include <hip/hip_runtime.h>

// B=128, S=1024, H=256
#define Bb 128
#define Ss 1024
#define Hh 256
#define NEGF 1e9f

typedef short bf16x8 __attribute__((ext_vector_type(8)));
typedef float f32x4 __attribute__((ext_vector_type(4)));

__device__ __forceinline__ short f2bf(float f) {
    union { float f; unsigned u; } c; c.f = f;
    return (short)((c.u + 0x8000u) >> 16);
}

__device__ __forceinline__ float bfhi2f(unsigned u) {
    union { unsigned u; float f; } c; c.u = u & 0xFFFF0000u; return c.f;
}
__device__ __forceinline__ float bflo2f(unsigned u) {
    union { unsigned u; float f; } c; c.u = u << 16; return c.f;
}

__device__ __forceinline__ bf16x8 ld_bf8_f32(const float* p) {
    const float4* p4 = (const float4*)p;
    float4 a = p4[0], b = p4[1];
    bf16x8 r;
    r[0] = f2bf(a.x); r[1] = f2bf(a.y); r[2] = f2bf(a.z); r[3] = f2bf(a.w);
    r[4] = f2bf(b.x); r[5] = f2bf(b.y); r[6] = f2bf(b.z); r[7] = f2bf(b.w);
    return r;
}

__device__ __forceinline__ float fast_tanh(float x) {
    float cl = fminf(fmaxf(x, -10.f), 10.f);
    float e = __expf(2.f * cl);
    return __builtin_fmaf(-2.f, __builtin_amdgcn_rcpf(e + 1.f), 1.f);
}

// async global->LDS, 16B per lane; dest = (wave-uniform) lds base + lane*16
__device__ __forceinline__ void stage16(const short* g, short* l) {
    __builtin_amdgcn_global_load_lds((const __attribute__((address_space(1))) void*)g,
                                     (__attribute__((address_space(3))) void*)l, 16, 0, 0);
}

// ---------------- prep: convert wg,wp -> bf16 (blocks 0..255); qbias_g (256..383)
__global__ __launch_bounds__(256) void prep_kernel(const float* __restrict__ wg,
                                                   const float* __restrict__ wp,
                                                   const float* __restrict__ query,
                                                   const float* __restrict__ wqg,
                                                   const float* __restrict__ bg,
                                                   short* __restrict__ wgb,
                                                   short* __restrict__ wpb,
                                                   float* __restrict__ qbias_g) {
    int blk = blockIdx.x, t = threadIdx.x;
    if (blk < 256) {
        int i = blk * 256 + t;
        wgb[i] = f2bf(wg[i]);
        wpb[i] = f2bf(wp[i]);
    } else {
        int b = blk - 256;
        const float4* qr = (const float4*)(query + b * Hh);
        const float4* wr = (const float4*)(wqg + t * Hh);
        float acc = 0.f;
#pragma unroll 8
        for (int i = 0; i < Hh / 4; ++i) {
            float4 q4 = qr[i], w4 = wr[i];
            acc += q4.x * w4.x + q4.y * w4.y + q4.z * w4.z + q4.w * w4.w;
        }
        qbias_g[b * Hh + t] = acc + bg[t];
    }
}

// ---------------- scores: persistent-W design. Grid = 256 blocks (1/CU).
// Whole W (256x256 bf16 = 128 KB) staged into dynamic LDS ONCE (one barrier),
// then each wave sweeps 128 A-rows in 2 barrier-free passes of 4 m-tiles.
// Per nc: 8 ds_read_b128 feed 4x8=32 back-to-back MFMAs + fused tanh*v epilogue.
template <int MASKED, int LOADF32>
__global__ __launch_bounds__(256, 1) void scores_persist(const float* __restrict__ reff,
                                                         const short* __restrict__ refb_in,
                                                         short* __restrict__ refb_out,
                                                         const short* __restrict__ Wbf,
                                                         const float* __restrict__ qbias,
                                                         const float* __restrict__ vvec,
                                                         const int* __restrict__ mask,
                                                         float* __restrict__ out) {
    extern __shared__ short Wlds[];   // 65536 shorts = 128 KB
    const int bk = blockIdx.x;        // 0..255
    const int t = threadIdx.x;
    const int wave = t >> 6, lane = t & 63, nl = lane & 15, quad = lane >> 4;
    const int b = bk >> 1;                         // batch
    const int srow0 = (bk & 1) * 512 + wave * 128; // this wave's row range in batch

    // staging scheme (r3-verified): thread t feeds read-lane (t&63) of LDS line
    // kb=(t>>6) [soff0] and kb=(t>>6)+4 [soff1] for each 16-row chunk
    const int soff0 = (t & 15) * Hh + (t >> 6) * 32 + ((t >> 4) & 3) * 8;  // shorts
    const int soff1 = soff0 + 128;
    const int dbase0 = wave * 512;          // shorts
    const int dbase1 = 2048 + wave * 512;

#pragma unroll
    for (int c = 0; c < 16; ++c) {
        const short* g = Wbf + c * 16 * Hh;
        stage16(g + soff0, &Wlds[c * 4096 + dbase0]);
        stage16(g + soff1, &Wlds[c * 4096 + dbase1]);
    }

    // hoist qbias/v (per-lane n = nc*16+nl) while W stages
    float qb[16], vv[16];
#pragma unroll
    for (int nc = 0; nc < 16; ++nc) {
        qb[nc] = qbias[b * Hh + nc * 16 + nl];
        vv[nc] = vvec[nc * 16 + nl];
    }
    __syncthreads();   // drains staging vmcnt; the ONLY barrier

    for (int pass = 0; pass < 2; ++pass) {
        const int rowbase = srow0 + pass * 64;

        // A prologue: 4 tiles x 8 fragments; A[m=tile*16+nl][k=kb*32+quad*8+j]
        bf16x8 af[4][8];
#pragma unroll
        for (int tile = 0; tile < 4; ++tile) {
            const size_t rowoff = ((size_t)b * Ss + rowbase + tile * 16 + nl) * Hh;
            if (LOADF32) {
                const float* rp = reff + rowoff;
#pragma unroll
                for (int kb = 0; kb < 8; ++kb)
                    af[tile][kb] = ld_bf8_f32(rp + kb * 32 + quad * 8);
                short* dst = refb_out + rowoff;
#pragma unroll
                for (int kb = 0; kb < 8; ++kb)
                    *(bf16x8*)(dst + kb * 32 + quad * 8) = af[tile][kb];
            } else {
                const short* rp = refb_in + rowoff;
#pragma unroll
                for (int kb = 0; kb < 8; ++kb)
                    af[tile][kb] = *(const bf16x8*)(rp + kb * 32 + quad * 8);
            }
        }

        float sc[4][4];
#pragma unroll
        for (int tile = 0; tile < 4; ++tile)
#pragma unroll
            for (int r = 0; r < 4; ++r) sc[tile][r] = 0.f;

        for (int nc = 0; nc < 16; ++nc) {
            bf16x8 bf[8];
#pragma unroll
            for (int kb = 0; kb < 8; ++kb)
                bf[kb] = *(const bf16x8*)&Wlds[nc * 4096 + kb * 512 + lane * 8];
#pragma unroll
            for (int tile = 0; tile < 4; ++tile) {
                f32x4 c = {0.f, 0.f, 0.f, 0.f};
#pragma unroll
                for (int kb = 0; kb < 8; ++kb)
                    c = __builtin_amdgcn_mfma_f32_16x16x32_bf16(af[tile][kb], bf[kb], c, 0, 0, 0);
                // C/D: col = lane&15 (= n-lane), row = quad*4 + r
#pragma unroll
                for (int r = 0; r < 4; ++r)
                    sc[tile][r] += fast_tanh(c[r] + qb[nc]) * vv[nc];
            }
        }

        // quad-local reduce over the 16 n-lanes, then write
#pragma unroll
        for (int tile = 0; tile < 4; ++tile) {
#pragma unroll
            for (int r = 0; r < 4; ++r) {
                float v = sc[tile][r];
                v += __shfl_xor(v, 1, 64);
                v += __shfl_xor(v, 2, 64);
                v += __shfl_xor(v, 4, 64);
                v += __shfl_xor(v, 8, 64);
                sc[tile][r] = v;
            }
            if (nl == 0) {
#pragma unroll
                for (int r = 0; r < 4; ++r) {
                    int m = rowbase + tile * 16 + quad * 4 + r;
                    float v = sc[tile][r];
                    if (MASKED) v -= (float)mask[b * Ss + m] * NEGF;
                    out[(size_t)b * Ss + m] = v;
                }
            }
        }
    }
}

// ---------------- Softmax over S per batch (mask applied) -> att ----------------
__global__ __launch_bounds__(1024) void softmax_kernel(const float* __restrict__ scores,
                                                       const int* __restrict__ mask,
                                                       float* __restrict__ att) {
    int b = blockIdx.x, t = threadIdx.x;
    __shared__ float red[16];
    int idx = b * Ss + t;
    float x = scores[idx] - (float)mask[idx] * NEGF;

    float m = x;
#pragma unroll
    for (int o = 1; o < 64; o <<= 1) m = fmaxf(m, __shfl_xor(m, o, 64));
    if ((t & 63) == 0) red[t >> 6] = m;
    __syncthreads();
    float M = red[0];
#pragma unroll
    for (int j = 1; j < 16; ++j) M = fmaxf(M, red[j]);
    __syncthreads();

    float e = __expf(x - M);
    float s = e;
#pragma unroll
    for (int o = 1; o < 64; o <<= 1) s += __shfl_xor(s, o, 64);
    if ((t & 63) == 0) red[t >> 6] = s;
    __syncthreads();
    float S = 0.f;
#pragma unroll
    for (int j = 0; j < 16; ++j) S += red[j];

    att[idx] = e * __builtin_amdgcn_rcpf(S);
}

// ---------------- Glimpse partial (bf16 ref): gpart[b,q,d] = sum_{s in 1/8th q} att*ref
__global__ __launch_bounds__(256) void glimpse_part(const unsigned* __restrict__ refb,
                                                    const float* __restrict__ att,
                                                    float* __restrict__ gpart) {
    int b = blockIdx.x, q = blockIdx.y, t = threadIdx.x;
    const int c = t & 31;      // 16B chunk: d = c*8 .. c*8+7
    const int rg = t >> 5;     // row group 0..7
    __shared__ float part[8][Hh];
    const unsigned* base = refb + ((size_t)(b * Ss + q * 128)) * (Hh / 2);
    const float* ap = att + b * Ss + q * 128;

    float acc[8] = {0.f, 0.f, 0.f, 0.f, 0.f, 0.f, 0.f, 0.f};
#pragma unroll 4
    for (int it = 0; it < 16; ++it) {
        int row = it * 8 + rg;
        float a = ap[row];
        uint4 v = *(const uint4*)(base + (size_t)row * (Hh / 2) + c * 4);
        acc[0] += a * bflo2f(v.x); acc[1] += a * bfhi2f(v.x);
        acc[2] += a * bflo2f(v.y); acc[3] += a * bfhi2f(v.y);
        acc[4] += a * bflo2f(v.z); acc[5] += a * bfhi2f(v.z);
        acc[6] += a * bflo2f(v.w); acc[7] += a * bfhi2f(v.w);
    }
#pragma unroll
    for (int j = 0; j < 8; ++j) part[rg][c * 8 + j] = acc[j];
    __syncthreads();
    float s = 0.f;
#pragma unroll
    for (int g = 0; g < 8; ++g) s += part[g][t];
    gpart[(size_t)(b * 8 + q) * Hh + t] = s;
}

// ---------------- qbias_p[b,h] = sum_d glimpse[b,d]*wqp[h,d] + bp[h] ------------
__global__ __launch_bounds__(256) void qbias_p_kernel(const float* __restrict__ gpart,
                                                      const float* __restrict__ query,
                                                      const float* __restrict__ wqp,
                                                      const float* __restrict__ bp,
                                                      float* __restrict__ out) {
    int b = blockIdx.x, t = threadIdx.x;
    __shared__ __align__(16) float gl[Hh];
    float g = query[b * Hh + t];
#pragma unroll
    for (int q = 0; q < 8; ++q) g += gpart[(b * 8 + q) * Hh + t];
    gl[t] = g;
    __syncthreads();
    const float4* wr = (const float4*)(wqp + t * Hh);
    const float4* gp = (const float4*)gl;
    float acc = 0.f;
#pragma unroll 8
    for (int i = 0; i < Hh / 4; ++i) {
        float4 w4 = wr[i];
        float4 g4 = gp[i];
        acc += w4.x * g4.x + w4.y * g4.y + w4.z * g4.z + w4.w * g4.w;
    }
    out[b * Hh + t] = acc + bp[t];
}

extern "C" void kernel_launch(void* const* d_in, const int* in_sizes, int n_in,
                              void* d_out, int out_size, void* d_ws, size_t ws_size,
                              hipStream_t stream) {
    const float* ref   = (const float*)d_in[0];
    const float* query = (const float*)d_in[1];
    const int*   mask  = (const int*)d_in[2];
    const float* wg    = (const float*)d_in[3];
    const float* bg    = (const float*)d_in[4];
    const float* wqg   = (const float*)d_in[5];
    const float* vg    = (const float*)d_in[6];
    const float* wp    = (const float*)d_in[7];
    const float* bp    = (const float*)d_in[8];
    const float* wqp   = (const float*)d_in[9];
    const float* vp    = (const float*)d_in[10];
    float* out = (float*)d_out;

    char* ws = (char*)d_ws;
    short* ref_bf   = (short*)(ws + 0);          // 64 MB (B*S*H bf16)
    size_t off = (size_t)Bb * Ss * Hh * 2;
    short* wg_bf    = (short*)(ws + off);               off += 131072;
    short* wp_bf    = (short*)(ws + off);               off += 131072;
    float* qbias_g  = (float*)(ws + off);               off += 131072;
    float* qbias_p  = (float*)(ws + off);               off += 131072;
    float* scores_g = (float*)(ws + off);               off += 524288;
    float* att      = (float*)(ws + off);               off += 524288;
    float* gpart    = (float*)(ws + off);               // 1 MB

    prep_kernel<<<384, 256, 0, stream>>>(wg, wp, query, wqg, bg, wg_bf, wp_bf, qbias_g);
    // glimpse scores: fp32 ref in, bf16 ref side-output from A-fragment registers
    scores_persist<0, 1><<<256, 256, 131072, stream>>>(
        ref, nullptr, ref_bf, wg_bf, qbias_g, vg, nullptr, scores_g);
    softmax_kernel<<<Bb, Ss, 0, stream>>>(scores_g, mask, att);
    glimpse_part<<<dim3(Bb, 8), 256, 0, stream>>>((const unsigned*)ref_bf, att, gpart);
    qbias_p_kernel<<<Bb, Hh, 0, stream>>>(gpart, query, wqp, bp, qbias_p);
    // pointer scores: bf16 ref in, masked, straight to d_out
    scores_persist<1, 0><<<256, 256, 131072, stream>>>(
        nullptr, ref_bf, nullptr, wp_bf, qbias_p, vp, mask, out);
}